// Round 1
// baseline (692.355 us; speedup 1.0000x reference)
//
#include <hip/hip_runtime.h>
#include <math.h>

#define D 256
#define NB_WANT 512

// ---------------------------------------------------------------------------
// K0: u = B @ q ; v = A^T @ u
// ---------------------------------------------------------------------------
__global__ __launch_bounds__(256) void mr_init(const float* __restrict__ q,
                                               const float* __restrict__ Bm,
                                               const float* __restrict__ Am,
                                               float* __restrict__ u,
                                               float* __restrict__ v) {
    __shared__ float sq[D];
    __shared__ float su[D];
    int tid = threadIdx.x;
    sq[tid] = q[tid];
    __syncthreads();
    // u_j = sum_k B[j,k] q_k   (each thread streams one row of B)
    float acc = 0.f;
    for (int k = 0; k < D; ++k) acc += Bm[tid * D + k] * sq[k];
    u[tid] = acc;
    su[tid] = acc;
    __syncthreads();
    // v_k = sum_j A[j,k] u_j   (coalesced across threads at fixed j)
    float vv = 0.f;
    for (int j = 0; j < D; ++j) vv += Am[j * D + tid] * su[j];
    v[tid] = vv;
}

// ---------------------------------------------------------------------------
// Main pass: one wave per slot-row. s_i = mem_i . v, online softmax with
// weighted accumulation of the raw memory row (4 floats per lane).
// Writes per-block (m, Z, w[256]) partials to workspace.
// ---------------------------------------------------------------------------
__device__ __forceinline__ float wave_reduce_sum(float s) {
    s += __shfl_xor(s, 32);
    s += __shfl_xor(s, 16);
    s += __shfl_xor(s, 8);
    s += __shfl_xor(s, 4);
    s += __shfl_xor(s, 2);
    s += __shfl_xor(s, 1);
    return s;
}

__device__ __forceinline__ void online_update(float s, const float4& x,
                                              float& m, float& Z, float4& w) {
    if (s > m) {                       // wave-uniform branch (s is reduced)
        float r = __expf(m - s);       // first time: exp(-inf)=0 zeroes Z,w
        Z = Z * r + 1.f;
        w.x = w.x * r + x.x;
        w.y = w.y * r + x.y;
        w.z = w.z * r + x.z;
        w.w = w.w * r + x.w;
        m = s;
    } else {
        float e = __expf(s - m);
        Z += e;
        w.x += e * x.x;
        w.y += e * x.y;
        w.z += e * x.z;
        w.w += e * x.w;
    }
}

__global__ __launch_bounds__(256) void mr_pass(const float* __restrict__ mem,
                                               const float* __restrict__ v,
                                               float* __restrict__ wsM,
                                               float* __restrict__ wsZ,
                                               float* __restrict__ wsW,
                                               int nslots, int nwaves) {
    const int lane = threadIdx.x & 63;
    const int wid  = threadIdx.x >> 6;
    const int gwave = blockIdx.x * 4 + wid;

    const float4 vv = ((const float4*)v)[lane];   // v[lane*4 .. lane*4+3]

    float  m = -INFINITY;
    float  Z = 0.f;
    float4 w = {0.f, 0.f, 0.f, 0.f};

    int slot = gwave;
    // 2-way unrolled grid-stride loop for memory-level parallelism
    for (; slot + nwaves < nslots; slot += 2 * nwaves) {
        float4 x0 = ((const float4*)(mem + (size_t)slot * D))[lane];
        float4 x1 = ((const float4*)(mem + (size_t)(slot + nwaves) * D))[lane];
        float s0 = x0.x * vv.x + x0.y * vv.y + x0.z * vv.z + x0.w * vv.w;
        float s1 = x1.x * vv.x + x1.y * vv.y + x1.z * vv.z + x1.w * vv.w;
        s0 = wave_reduce_sum(s0);
        s1 = wave_reduce_sum(s1);
        online_update(s0, x0, m, Z, w);
        online_update(s1, x1, m, Z, w);
    }
    for (; slot < nslots; slot += nwaves) {
        float4 x = ((const float4*)(mem + (size_t)slot * D))[lane];
        float s = x.x * vv.x + x.y * vv.y + x.z * vv.z + x.w * vv.w;
        s = wave_reduce_sum(s);
        online_update(s, x, m, Z, w);
    }

    // ---- block combine (4 waves) via LDS ----
    __shared__ float lm[4];
    __shared__ float lz[4];
    __shared__ float lw[4][D];
    if (lane == 0) { lm[wid] = m; lz[wid] = Z; }
    *(float4*)&lw[wid][lane * 4] = w;
    __syncthreads();

    int tid = threadIdx.x;
    float M = fmaxf(fmaxf(lm[0], lm[1]), fmaxf(lm[2], lm[3]));
    float wacc = 0.f;
    float zacc = 0.f;
    for (int wq = 0; wq < 4; ++wq) {
        float f = __expf(lm[wq] - M);
        wacc += lw[wq][tid] * f;
        zacc += lz[wq] * f;
    }
    wsW[blockIdx.x * D + tid] = wacc;
    if (tid == 0) {
        wsM[blockIdx.x] = M;
        wsZ[blockIdx.x] = zacc;
    }
}

// ---------------------------------------------------------------------------
// Combine partials, o = C (w/Z), u += o, v = A^T u (or write out on last hop)
// ---------------------------------------------------------------------------
__global__ __launch_bounds__(256) void mr_combine(const float* __restrict__ wsM,
                                                  const float* __restrict__ wsZ,
                                                  const float* __restrict__ wsW,
                                                  const float* __restrict__ Cm,
                                                  const float* __restrict__ Am,
                                                  float* __restrict__ u,
                                                  float* __restrict__ v,
                                                  float* __restrict__ out,
                                                  int nblocks, int last) {
    __shared__ float sw[D];
    __shared__ float su[D];
    int tid = threadIdx.x;

    float M = -INFINITY;
    for (int b = 0; b < nblocks; ++b) M = fmaxf(M, wsM[b]);

    float Z = 0.f, wt = 0.f;
    for (int b = 0; b < nblocks; ++b) {
        float f = __expf(wsM[b] - M);
        Z  += wsZ[b] * f;
        wt += wsW[b * D + tid] * f;
    }
    sw[tid] = wt / Z;
    __syncthreads();

    // o_j = sum_k C[j,k] * w_k
    float o = 0.f;
    for (int k = 0; k < D; ++k) o += Cm[tid * D + k] * sw[k];

    float un = u[tid] + o;
    u[tid] = un;
    su[tid] = un;
    if (last) out[tid] = un;
    __syncthreads();

    if (!last) {
        // v_k = sum_j A[j,k] u_j  (coalesced across threads)
        float vv = 0.f;
        for (int j = 0; j < D; ++j) vv += Am[j * D + tid] * su[j];
        v[tid] = vv;
    }
}

// ---------------------------------------------------------------------------
extern "C" void kernel_launch(void* const* d_in, const int* in_sizes, int n_in,
                              void* d_out, int out_size, void* d_ws, size_t ws_size,
                              hipStream_t stream) {
    const float* mem = (const float*)d_in[0];
    const float* q   = (const float*)d_in[1];
    const float* A   = (const float*)d_in[2];
    const float* B   = (const float*)d_in[3];
    const float* C   = (const float*)d_in[4];
    float* out = (float*)d_out;
    float* ws  = (float*)d_ws;

    const int nslots = in_sizes[0] / D;   // 100000

    // workspace budget: 2*D (u,v) + nb*(2 + D) floats
    long wsf = (long)(ws_size / 4);
    int nb = NB_WANT;
    long need = 2L * D + (long)nb * (2 + D);
    if (need > wsf) {
        nb = (int)((wsf - 2L * D) / (2 + D));
        if (nb < 1) nb = 1;
    }

    float* u   = ws;
    float* v   = ws + D;
    float* wsM = ws + 2 * D;
    float* wsZ = wsM + nb;
    float* wsW = wsZ + nb;

    mr_init<<<1, 256, 0, stream>>>(q, B, A, u, v);
    for (int hop = 0; hop < 3; ++hop) {
        mr_pass<<<nb, 256, 0, stream>>>(mem, v, wsM, wsZ, wsW, nslots, nb * 4);
        mr_combine<<<1, 256, 0, stream>>>(wsM, wsZ, wsW, C, A, u, v, out,
                                          nb, hop == 2 ? 1 : 0);
    }
}

// Round 2
// 272.213 us; speedup vs baseline: 2.5434x; 2.5434x over previous
//
#include <hip/hip_runtime.h>
#include <math.h>

#define D 256
#define NB 512
#define PASS_THREADS 512
#define PASS_WAVES (PASS_THREADS / 64)

// ---------------------------------------------------------------------------
// wave-wide reductions (64 lanes)
// ---------------------------------------------------------------------------
__device__ __forceinline__ float wave_reduce_sum(float s) {
    s += __shfl_xor(s, 32);
    s += __shfl_xor(s, 16);
    s += __shfl_xor(s, 8);
    s += __shfl_xor(s, 4);
    s += __shfl_xor(s, 2);
    s += __shfl_xor(s, 1);
    return s;
}

__device__ __forceinline__ float wave_reduce_max(float s) {
    s = fmaxf(s, __shfl_xor(s, 32));
    s = fmaxf(s, __shfl_xor(s, 16));
    s = fmaxf(s, __shfl_xor(s, 8));
    s = fmaxf(s, __shfl_xor(s, 4));
    s = fmaxf(s, __shfl_xor(s, 2));
    s = fmaxf(s, __shfl_xor(s, 1));
    return s;
}

// ---------------------------------------------------------------------------
// K0: u = B @ q ; v = A^T @ u   (1 block, 1024 threads, quad-split matvecs)
// ---------------------------------------------------------------------------
__global__ __launch_bounds__(1024) void mr_init(const float* __restrict__ q,
                                                const float* __restrict__ Bm,
                                                const float* __restrict__ Am,
                                                float* __restrict__ u,
                                                float* __restrict__ v) {
    __shared__ __align__(16) float sq[D];
    __shared__ float su[D];
    __shared__ float part[4][D];
    const int tid = threadIdx.x;

    if (tid < D) sq[tid] = q[tid];
    __syncthreads();

    // u_j = sum_k B[j,k] q_k : thread (j = tid>>2, quarter = tid&3) does 64 k's
    {
        const int j = tid >> 2, qd = tid & 3;
        const float4* Br = (const float4*)(Bm + (size_t)j * D + qd * 64);
        const float4* qr = (const float4*)(sq + qd * 64);
        float acc = 0.f;
#pragma unroll
        for (int i = 0; i < 16; ++i) {
            float4 b4 = Br[i];
            float4 q4 = qr[i];
            acc += b4.x * q4.x + b4.y * q4.y + b4.z * q4.z + b4.w * q4.w;
        }
        part[qd][j] = acc;
    }
    __syncthreads();
    if (tid < D) {
        float uu = part[0][tid] + part[1][tid] + part[2][tid] + part[3][tid];
        u[tid] = uu;
        su[tid] = uu;
    }
    __syncthreads();

    // v_k = sum_j A[j,k] u_j : coalesced across k, quad-split over j
    {
        const int k = tid & (D - 1), h = tid >> 8;
        const int j0 = h * 64;
        float acc = 0.f;
#pragma unroll 8
        for (int jj = 0; jj < 64; ++jj)
            acc += Am[(size_t)(j0 + jj) * D + k] * su[j0 + jj];
        part[h][k] = acc;
    }
    __syncthreads();
    if (tid < D)
        v[tid] = part[0][tid] + part[1][tid] + part[2][tid] + part[3][tid];
}

// ---------------------------------------------------------------------------
// online softmax update (s is wave-uniform -> branch is divergence-free)
// ---------------------------------------------------------------------------
__device__ __forceinline__ void online_update(float s, const float4& x,
                                              float& m, float& Z, float4& w) {
    if (s > m) {
        float r = __expf(m - s);      // first time: exp(-inf)=0 zeroes Z,w
        Z = Z * r + 1.f;
        w.x = w.x * r + x.x;
        w.y = w.y * r + x.y;
        w.z = w.z * r + x.z;
        w.w = w.w * r + x.w;
        m = s;
    } else {
        float e = __expf(s - m);
        Z += e;
        w.x += e * x.x;
        w.y += e * x.y;
        w.z += e * x.z;
        w.w += e * x.w;
    }
}

// ---------------------------------------------------------------------------
// Main pass: one wave per slot-row, 8 waves/block, 4-deep unroll for MLP.
// ---------------------------------------------------------------------------
__global__ __launch_bounds__(PASS_THREADS) void mr_pass(
        const float* __restrict__ mem, const float* __restrict__ v,
        float* __restrict__ wsM, float* __restrict__ wsZ,
        float* __restrict__ wsW, int nslots, int nwaves) {
    const int lane = threadIdx.x & 63;
    const int wid  = threadIdx.x >> 6;
    const int gwave = blockIdx.x * PASS_WAVES + wid;
    const int stride = nwaves;

    const float4 vv = ((const float4*)v)[lane];

    float  m = -INFINITY;
    float  Z = 0.f;
    float4 w = {0.f, 0.f, 0.f, 0.f};

    int slot = gwave;
    for (; slot + 3 * stride < nslots; slot += 4 * stride) {
        float4 x0 = ((const float4*)(mem + (size_t)slot * D))[lane];
        float4 x1 = ((const float4*)(mem + (size_t)(slot + stride) * D))[lane];
        float4 x2 = ((const float4*)(mem + (size_t)(slot + 2 * stride) * D))[lane];
        float4 x3 = ((const float4*)(mem + (size_t)(slot + 3 * stride) * D))[lane];
        float s0 = x0.x * vv.x + x0.y * vv.y + x0.z * vv.z + x0.w * vv.w;
        float s1 = x1.x * vv.x + x1.y * vv.y + x1.z * vv.z + x1.w * vv.w;
        float s2 = x2.x * vv.x + x2.y * vv.y + x2.z * vv.z + x2.w * vv.w;
        float s3 = x3.x * vv.x + x3.y * vv.y + x3.z * vv.z + x3.w * vv.w;
        s0 = wave_reduce_sum(s0);
        s1 = wave_reduce_sum(s1);
        s2 = wave_reduce_sum(s2);
        s3 = wave_reduce_sum(s3);
        online_update(s0, x0, m, Z, w);
        online_update(s1, x1, m, Z, w);
        online_update(s2, x2, m, Z, w);
        online_update(s3, x3, m, Z, w);
    }
    for (; slot < nslots; slot += stride) {
        float4 x = ((const float4*)(mem + (size_t)slot * D))[lane];
        float s = x.x * vv.x + x.y * vv.y + x.z * vv.z + x.w * vv.w;
        s = wave_reduce_sum(s);
        online_update(s, x, m, Z, w);
    }

    // ---- block combine (8 waves) via LDS ----
    __shared__ float lm[PASS_WAVES];
    __shared__ float lz[PASS_WAVES];
    __shared__ __align__(16) float lw[PASS_WAVES][D];
    if (lane == 0) { lm[wid] = m; lz[wid] = Z; }
    *(float4*)&lw[wid][lane * 4] = w;
    __syncthreads();

    const int tid = threadIdx.x;
    if (tid < D) {
        float M = lm[0];
#pragma unroll
        for (int wq = 1; wq < PASS_WAVES; ++wq) M = fmaxf(M, lm[wq]);
        float wacc = 0.f, zacc = 0.f;
#pragma unroll
        for (int wq = 0; wq < PASS_WAVES; ++wq) {
            float fq = __expf(lm[wq] - M);
            wacc += lw[wq][tid] * fq;
            zacc += lz[wq] * fq;
        }
        wsW[(size_t)blockIdx.x * D + tid] = wacc;
        if (tid == 0) {
            wsM[blockIdx.x] = M;
            wsZ[blockIdx.x] = zacc;
        }
    }
}

// ---------------------------------------------------------------------------
// Combine partials (parallel!), o = C (w/Z), u += o, v = A^T u
// 1 block x 1024 threads.
// ---------------------------------------------------------------------------
__global__ __launch_bounds__(1024) void mr_combine(
        const float* __restrict__ wsM, const float* __restrict__ wsZ,
        const float* __restrict__ wsW, const float* __restrict__ Cm,
        const float* __restrict__ Am, float* __restrict__ u,
        float* __restrict__ v, float* __restrict__ out, int nb, int last) {
    __shared__ float f[NB];
    __shared__ float red[16];
    __shared__ float sMZ[2];
    __shared__ float part[4][D];
    __shared__ __align__(16) float sw[D];
    __shared__ float su[D];
    const int tid = threadIdx.x;
    const int lane = tid & 63, wv = tid >> 6;

    // Phase A: global max over nb partials (parallel)
    float lm = -INFINITY;
    for (int b = tid; b < nb; b += 1024) lm = fmaxf(lm, wsM[b]);
    lm = wave_reduce_max(lm);
    if (lane == 0) red[wv] = lm;
    __syncthreads();
    if (tid == 0) {
        float M = red[0];
#pragma unroll
        for (int i = 1; i < 16; ++i) M = fmaxf(M, red[i]);
        sMZ[0] = M;
    }
    __syncthreads();
    const float M = sMZ[0];

    // Phase A2: f[b] = exp(m_b - M); Z = sum z_b f_b  (parallel)
    float zp = 0.f;
    for (int b = tid; b < nb; b += 1024) {
        float fb = __expf(wsM[b] - M);
        f[b] = fb;
        zp += wsZ[b] * fb;
    }
    zp = wave_reduce_sum(zp);
    if (lane == 0) red[wv] = zp;
    __syncthreads();
    if (tid == 0) {
        float Z = 0.f;
#pragma unroll
        for (int i = 0; i < 16; ++i) Z += red[i];
        sMZ[1] = Z;
    }
    __syncthreads();
    const float Z = sMZ[1];

    // Phase B: w_c = sum_b wsW[b][c] * f[b]  — 4 chunks x 256 components
    {
        const int c = tid & (D - 1);
        const int chunk = tid >> 8;
        const int bpc = nb >> 2;
        const int b0 = chunk * bpc;
        const int b1 = b0 + bpc;
        float acc = 0.f;
#pragma unroll 8
        for (int b = b0; b < b1; ++b)
            acc += wsW[(size_t)b * D + c] * f[b];
        part[chunk][c] = acc;
    }
    __syncthreads();
    if (tid < D)
        sw[tid] = (part[0][tid] + part[1][tid] + part[2][tid] + part[3][tid]) / Z;
    __syncthreads();

    // Phase C: o_j = sum_k C[j,k] sw[k]  (quad-split rows)
    {
        const int j = tid >> 2, qd = tid & 3;
        const float4* Cr = (const float4*)(Cm + (size_t)j * D + qd * 64);
        const float4* wr = (const float4*)(sw + qd * 64);
        float acc = 0.f;
#pragma unroll
        for (int i = 0; i < 16; ++i) {
            float4 c4 = Cr[i];
            float4 w4 = wr[i];
            acc += c4.x * w4.x + c4.y * w4.y + c4.z * w4.z + c4.w * w4.w;
        }
        part[qd][j] = acc;
    }
    __syncthreads();
    if (tid < D) {
        float o = part[0][tid] + part[1][tid] + part[2][tid] + part[3][tid];
        float un = u[tid] + o;
        u[tid] = un;
        su[tid] = un;
        if (last) out[tid] = un;
    }
    __syncthreads();

    if (!last) {
        // v_k = sum_j A[j,k] u_j  (coalesced across k, quad-split over j)
        const int k = tid & (D - 1), h = tid >> 8;
        const int j0 = h * 64;
        float acc = 0.f;
#pragma unroll 8
        for (int jj = 0; jj < 64; ++jj)
            acc += Am[(size_t)(j0 + jj) * D + k] * su[j0 + jj];
        part[h][k] = acc;
        __syncthreads();
        if (tid < D)
            v[tid] = part[0][tid] + part[1][tid] + part[2][tid] + part[3][tid];
    }
}

// ---------------------------------------------------------------------------
extern "C" void kernel_launch(void* const* d_in, const int* in_sizes, int n_in,
                              void* d_out, int out_size, void* d_ws, size_t ws_size,
                              hipStream_t stream) {
    const float* mem = (const float*)d_in[0];
    const float* q   = (const float*)d_in[1];
    const float* A   = (const float*)d_in[2];
    const float* B   = (const float*)d_in[3];
    const float* C   = (const float*)d_in[4];
    float* out = (float*)d_out;
    float* ws  = (float*)d_ws;

    const int nslots = in_sizes[0] / D;   // 100000

    long wsf = (long)(ws_size / 4);
    int nb = NB;
    long need = 2L * D + (long)nb * (2 + D);
    if (need > wsf) {
        nb = (int)((wsf - 2L * D) / (2 + D));
        nb &= ~3;
        if (nb < 4) nb = 4;
    }

    float* u   = ws;
    float* v   = ws + D;
    float* wsM = ws + 2 * D;
    float* wsZ = wsM + nb;
    float* wsW = wsZ + nb;

    mr_init<<<1, 1024, 0, stream>>>(q, B, A, u, v);
    for (int hop = 0; hop < 3; ++hop) {
        mr_pass<<<nb, PASS_THREADS, 0, stream>>>(mem, v, wsM, wsZ, wsW,
                                                 nslots, nb * PASS_WAVES);
        mr_combine<<<1, 1024, 0, stream>>>(wsM, wsZ, wsW, C, A, u, v, out,
                                           nb, hop == 2 ? 1 : 0);
    }
}